// Round 1
// baseline (3220.972 us; speedup 1.0000x reference)
//
#include <hip/hip_runtime.h>
#include <math.h>

// ============================================================================
// CancerGATE: 3x embed Dense(relu) -> concat(384) -> GATConv(4h,128) relu
//             -> GATConv(4h,64) -> decoder (tied fc1^T, fc0^T, head-mean,
//             3x Dense sigmoid)
// Round 0: fully fp32, correctness-first. CSR built on-device per call.
// ============================================================================

#define LRELU_SLOPE 0.2f

// ---------------------------------------------------------------------------
// Generic fp32 GEMM: C[M,N] = act(A[M,K] @ op(B) + bias)
// BT=false: B is [K,N] row-major (ldb = N stride)
// BT=true : B is [N,K] row-major (ldb = K stride), i.e. C = A @ B^T
// ACT: 0 = none, 1 = relu, 2 = sigmoid
// Tile 64x64, BK=16, 256 threads, 4x4 microtile. N must be mult of 64,
// K mult of 16 (true for all shapes here). M ragged (guarded).
// ---------------------------------------------------------------------------
template<int ACT, bool BT>
__global__ __launch_bounds__(256) void gemm64(
    const float* __restrict__ A, int lda,
    const float* __restrict__ B, int ldb,
    const float* __restrict__ bias,
    float* __restrict__ C, int ldc,
    int M, int K)
{
    __shared__ float As[16][68];
    __shared__ float Bs[16][68];

    const int tid = threadIdx.x;
    const int tx = tid & 15;       // 0..15  (cols)
    const int ty = tid >> 4;       // 0..15  (rows)
    const int bm = blockIdx.x * 64;
    const int bn = blockIdx.y * 64;

    float acc[4][4] = {};

    const int arow = tid >> 2;          // 0..63
    const int ac4  = (tid & 3) << 2;    // 0,4,8,12

    for (int k0 = 0; k0 < K; k0 += 16) {
        // --- load A tile: rows bm+arow, cols k0+ac4..+3 -> As[k][row]
        {
            int r = bm + arow;
            float4 v = make_float4(0.f, 0.f, 0.f, 0.f);
            if (r < M) v = *(const float4*)(A + (size_t)r * lda + k0 + ac4);
            As[ac4 + 0][arow] = v.x;
            As[ac4 + 1][arow] = v.y;
            As[ac4 + 2][arow] = v.z;
            As[ac4 + 3][arow] = v.w;
        }
        // --- load B tile -> Bs[k][n]
        if (!BT) {
            int r = k0 + (tid >> 4);
            int c = (tid & 15) << 2;
            float4 v = *(const float4*)(B + (size_t)r * ldb + bn + c);
            *(float4*)&Bs[tid >> 4][c] = v;
        } else {
            int nn = tid >> 2;              // 0..63
            int kk = (tid & 3) << 2;        // 0,4,8,12
            float4 v = *(const float4*)(B + (size_t)(bn + nn) * ldb + k0 + kk);
            Bs[kk + 0][nn] = v.x;
            Bs[kk + 1][nn] = v.y;
            Bs[kk + 2][nn] = v.z;
            Bs[kk + 3][nn] = v.w;
        }
        __syncthreads();

        #pragma unroll
        for (int k = 0; k < 16; ++k) {
            float4 a = *(const float4*)&As[k][ty << 2];
            float4 b = *(const float4*)&Bs[k][tx << 2];
            float av[4] = {a.x, a.y, a.z, a.w};
            float bv[4] = {b.x, b.y, b.z, b.w};
            #pragma unroll
            for (int i = 0; i < 4; ++i)
                #pragma unroll
                for (int j = 0; j < 4; ++j)
                    acc[i][j] += av[i] * bv[j];
        }
        __syncthreads();
    }

    // --- epilogue
    #pragma unroll
    for (int i = 0; i < 4; ++i) {
        int r = bm + (ty << 2) + i;
        if (r >= M) continue;
        #pragma unroll
        for (int j = 0; j < 4; ++j) {
            int c = bn + (tx << 2) + j;
            float v = acc[i][j] + (bias ? bias[c] : 0.f);
            if (ACT == 1) v = fmaxf(v, 0.f);
            else if (ACT == 2) v = 1.f / (1.f + expf(-v));
            C[(size_t)r * ldc + c] = v;
        }
    }
}

// ---------------------------------------------------------------------------
// CSR build
// ---------------------------------------------------------------------------
__global__ void hist_kernel(const int* __restrict__ dst, int* __restrict__ deg, int E)
{
    int i = blockIdx.x * blockDim.x + threadIdx.x;
    if (i < E) atomicAdd(&deg[dst[i]], 1);
}

__global__ void chunk_sums(const int* __restrict__ deg, int* __restrict__ sums, int N)
{
    __shared__ int s[256];
    int t = threadIdx.x;
    int base = blockIdx.x * 1024;
    int v = 0;
    for (int i = t; i < 1024; i += 256) {
        int g = base + i;
        if (g < N) v += deg[g];
    }
    s[t] = v;
    __syncthreads();
    for (int off = 128; off > 0; off >>= 1) {
        if (t < off) s[t] += s[t + off];
        __syncthreads();
    }
    if (t == 0) sums[blockIdx.x] = s[0];
}

__global__ void scan_base(const int* __restrict__ sums, int* __restrict__ base,
                          int* __restrict__ rowptr, int nch, int N)
{
    if (threadIdx.x == 0 && blockIdx.x == 0) {
        int run = 0;
        for (int c = 0; c < nch; ++c) { base[c] = run; run += sums[c]; }
        rowptr[N] = run;
    }
}

__global__ void scan_chunks(const int* __restrict__ deg, const int* __restrict__ cbase,
                            int* __restrict__ rowptr, int N)
{
    __shared__ int s[1024];
    int t = threadIdx.x;
    int g = blockIdx.x * 1024 + t;
    int v = (g < N) ? deg[g] : 0;
    s[t] = v;
    __syncthreads();
    for (int off = 1; off < 1024; off <<= 1) {
        int x = (t >= off) ? s[t - off] : 0;
        __syncthreads();
        s[t] += x;
        __syncthreads();
    }
    if (g < N) rowptr[g] = cbase[blockIdx.x] + s[t] - v;   // exclusive scan
}

__global__ void scatter_kernel(const int* __restrict__ src, const int* __restrict__ dst,
                               const int* __restrict__ rowptr, int* __restrict__ wcount,
                               int* __restrict__ esrc, int E)
{
    int i = blockIdx.x * blockDim.x + threadIdx.x;
    if (i < E) {
        int d = dst[i];
        int p = rowptr[d] + atomicAdd(&wcount[d], 1);
        esrc[p] = src[i];
    }
}

// ---------------------------------------------------------------------------
// el/er: el[n,h] = sum_d z[n,h,d]*al[h,d]; er likewise with ar.
// One wave per (n,h).
// ---------------------------------------------------------------------------
__global__ void attn_scores(const float* __restrict__ z,
                            const float* __restrict__ al, const float* __restrict__ ar,
                            float* __restrict__ el, float* __restrict__ er,
                            int N, int H, int D)
{
    int wid = (blockIdx.x * blockDim.x + threadIdx.x) >> 6;
    int lane = threadIdx.x & 63;
    int n = wid / H, h = wid % H;
    if (n >= N) return;
    float sl = 0.f, sr = 0.f;
    const float* zp = z + (size_t)n * H * D + (size_t)h * D;
    for (int d = lane; d < D; d += 64) {
        float zv = zp[d];
        sl += zv * al[h * D + d];
        sr += zv * ar[h * D + d];
    }
    #pragma unroll
    for (int off = 32; off > 0; off >>= 1) {
        sl += __shfl_down(sl, off);
        sr += __shfl_down(sr, off);
    }
    if (lane == 0) { el[n * H + h] = sl; er[n * H + h] = sr; }
}

// ---------------------------------------------------------------------------
// Per-dst-node edge-softmax + aggregation (online, chunked).
// One block (256 thr) per node. rst holds residual on entry; on exit:
//   rst = relu( agg/(s+1e-9) + residual )     (relu fused for both layers)
// HD = H*D in {512, 256}; H = 4.
// ---------------------------------------------------------------------------
template<int HD, int D>
__global__ __launch_bounds__(256) void gat_aggregate(
    const int* __restrict__ rowptr, const int* __restrict__ esrc,
    const float* __restrict__ el, const float* __restrict__ er,
    const float* __restrict__ z, float* __restrict__ rst, int N)
{
    constexpr int H = HD / D;            // 4
    constexpr int EPT = HD / 256;        // 2 (layer0) or 1 (layer1)
    const int n = blockIdx.x;
    if (n >= N) return;
    const int t = threadIdx.x;
    const int myhead = t >> 6;           // works for both D=128 (t*2/128) & D=64

    __shared__ float s_e[256 * H];
    __shared__ int   s_src[256];
    __shared__ float s_m[H], s_sum[H], s_scale[H], s_er[H];

    if (t < H) {
        s_er[t] = er[n * H + t];
        s_m[t] = -INFINITY;
        s_sum[t] = 0.f;
    }
    float acc[EPT] = {};

    const int e0 = rowptr[n], e1 = rowptr[n + 1];

    for (int c0 = e0; c0 < e1; c0 += 256) {
        const int cnt = min(256, e1 - c0);
        if (t < cnt) s_src[t] = esrc[c0 + t];
        __syncthreads();

        // edge scores for this chunk
        for (int idx = t; idx < cnt * H; idx += 256) {
            int j = idx >> 2, h = idx & 3;
            float v = el[s_src[j] * H + h] + s_er[h];
            s_e[j * H + h] = (v > 0.f) ? v : LRELU_SLOPE * v;
        }
        __syncthreads();

        // per-head online max/sum (thread h handles head h)
        if (t < H) {
            float mo = s_m[t];
            float cm = mo;
            for (int j = 0; j < cnt; ++j) cm = fmaxf(cm, s_e[j * H + t]);
            float scale = expf(mo - cm);
            float ssum = s_sum[t] * scale;
            for (int j = 0; j < cnt; ++j) {
                float ex = expf(s_e[j * H + t] - cm);
                s_e[j * H + t] = ex;
                ssum += ex;
            }
            s_m[t] = cm; s_sum[t] = ssum; s_scale[t] = scale;
        }
        __syncthreads();

        // rescale accumulator, gather-accumulate z[src]
        float sc = s_scale[myhead];
        #pragma unroll
        for (int i = 0; i < EPT; ++i) acc[i] *= sc;

        for (int j = 0; j < cnt; ++j) {
            const float a = s_e[j * H + myhead];
            const float* zp = z + (size_t)s_src[j] * HD + t * EPT;
            if (EPT == 2) {
                float2 v = *(const float2*)zp;
                acc[0] += a * v.x;
                acc[1] += a * v.y;
            } else {
                acc[0] += a * zp[0];
            }
        }
        __syncthreads();   // protect s_e/s_src for next chunk
    }

    __syncthreads();
    const float denom = s_sum[myhead] + 1e-9f;
    const size_t base = (size_t)n * HD + t * EPT;
    #pragma unroll
    for (int i = 0; i < EPT; ++i) {
        float v = acc[i] / denom + rst[base + i];
        rst[base + i] = fmaxf(v, 0.f);
    }
}

// ---------------------------------------------------------------------------
// head-mean: dm[n,j] = mean_h d2[n, h*96 + j], H=4
// ---------------------------------------------------------------------------
__global__ void mean_heads(const float* __restrict__ d2, float* __restrict__ dm, int N)
{
    int i = blockIdx.x * blockDim.x + threadIdx.x;
    if (i >= N * 96) return;
    int n = i / 96, j = i % 96;
    const float* p = d2 + (size_t)n * 384;
    dm[i] = 0.25f * (p[j] + p[96 + j] + p[192 + j] + p[288 + j]);
}

// ---------------------------------------------------------------------------
// host side
// ---------------------------------------------------------------------------
extern "C" void kernel_launch(void* const* d_in, const int* in_sizes, int n_in,
                              void* d_out, int out_size, void* d_ws, size_t ws_size,
                              hipStream_t stream)
{
    const float* feat0 = (const float*)d_in[0];
    const float* feat1 = (const float*)d_in[1];
    const float* feat2 = (const float*)d_in[2];
    const int*   srcp  = (const int*)d_in[3];
    const int*   dstp  = (const int*)d_in[4];
    const float* W_emb[3] = {(const float*)d_in[5], (const float*)d_in[7], (const float*)d_in[9]};
    const float* b_emb[3] = {(const float*)d_in[6], (const float*)d_in[8], (const float*)d_in[10]};
    const float* fc0  = (const float*)d_in[11];
    const float* al0  = (const float*)d_in[12];
    const float* ar0  = (const float*)d_in[13];
    const float* res0 = (const float*)d_in[14];
    const float* fc1  = (const float*)d_in[15];
    const float* al1  = (const float*)d_in[16];
    const float* ar1  = (const float*)d_in[17];
    const float* res1 = (const float*)d_in[18];
    const float* Wd[3] = {(const float*)d_in[19], (const float*)d_in[21], (const float*)d_in[23]};
    const float* bd[3] = {(const float*)d_in[20], (const float*)d_in[22], (const float*)d_in[24]};
    float* out = (float*)d_out;

    const int N = in_sizes[0] / 512;     // 50000
    const int E = in_sizes[3];           // 1600000

    // ---- workspace layout (with aliasing reuse) ----
    char* w = (char*)d_ws;
    size_t off = 0;
    auto alloc = [&](size_t bytes) -> char* {
        char* p = w + off;
        off = (off + bytes + 255) & ~(size_t)255;
        return p;
    };
    float* h0   = (float*)alloc((size_t)N * 384 * 4);   // emb concat
    float* z0   = (float*)alloc((size_t)N * 512 * 4);   // layer0 projected
    float* rst0 = (float*)alloc((size_t)N * 512 * 4);   // layer0 out (h1)
    float* el0  = (float*)alloc((size_t)N * 4 * 4);
    float* er0  = (float*)alloc((size_t)N * 4 * 4);
    float* el1  = (float*)alloc((size_t)N * 4 * 4);
    float* er1  = (float*)alloc((size_t)N * 4 * 4);
    int* deg    = (int*)alloc((size_t)N * 4);
    int* rowptr = (int*)alloc((size_t)(N + 1) * 4);
    int* wcount = (int*)alloc((size_t)N * 4);
    int* csums  = (int*)alloc(64 * 4);
    int* cbase  = (int*)alloc(64 * 4);
    int* esrc   = (int*)alloc((size_t)E * 4);
    (void)ws_size; (void)n_in; (void)out_size;

    // aliases (lifetimes verified: each region dead before reuse)
    float* z1   = h0;      // [N,256]
    float* rst1 = z0;      // [N,256]  (h2, relu-fused)
    float* d1   = rst0;    // [N,512]
    float* d2   = h0;      // [N,384]
    float* dm   = z0;      // [N,96]

    auto launch_gemm = [&](const float* A, int lda, const float* B, int ldb,
                           const float* bias, float* C, int ldc,
                           int M, int Nn, int K, int act, bool bt) {
        dim3 grid((M + 63) / 64, Nn / 64), blk(256);
        if (!bt) {
            if (act == 0)      gemm64<0,false><<<grid, blk, 0, stream>>>(A, lda, B, ldb, bias, C, ldc, M, K);
            else if (act == 1) gemm64<1,false><<<grid, blk, 0, stream>>>(A, lda, B, ldb, bias, C, ldc, M, K);
            else               gemm64<2,false><<<grid, blk, 0, stream>>>(A, lda, B, ldb, bias, C, ldc, M, K);
        } else {
            if (act == 0)      gemm64<0,true><<<grid, blk, 0, stream>>>(A, lda, B, ldb, bias, C, ldc, M, K);
            else if (act == 1) gemm64<1,true><<<grid, blk, 0, stream>>>(A, lda, B, ldb, bias, C, ldc, M, K);
            else               gemm64<2,true><<<grid, blk, 0, stream>>>(A, lda, B, ldb, bias, C, ldc, M, K);
        }
    };

    // ---- CSR build (graph shared by both GAT layers) ----
    hipMemsetAsync(deg, 0, (size_t)N * 4, stream);
    hipMemsetAsync(wcount, 0, (size_t)N * 4, stream);
    hist_kernel<<<(E + 255) / 256, 256, 0, stream>>>(dstp, deg, E);
    const int nch = (N + 1023) / 1024;
    chunk_sums<<<nch, 256, 0, stream>>>(deg, csums, N);
    scan_base<<<1, 1, 0, stream>>>(csums, cbase, rowptr, nch, N);
    scan_chunks<<<nch, 1024, 0, stream>>>(deg, cbase, rowptr, N);
    scatter_kernel<<<(E + 255) / 256, 256, 0, stream>>>(srcp, dstp, rowptr, wcount, esrc, E);

    // ---- embedding: h0 = concat(relu(featI @ W_embI + b_embI)) ----
    launch_gemm(feat0, 512, W_emb[0], 128, b_emb[0], h0 + 0,   384, N, 128, 512, 1, false);
    launch_gemm(feat1, 512, W_emb[1], 128, b_emb[1], h0 + 128, 384, N, 128, 512, 1, false);
    launch_gemm(feat2, 512, W_emb[2], 128, b_emb[2], h0 + 256, 384, N, 128, 512, 1, false);

    // ---- GAT layer 0 ----
    launch_gemm(h0, 384, fc0,  512, nullptr, z0,   512, N, 512, 384, 0, false);
    launch_gemm(h0, 384, res0, 512, nullptr, rst0, 512, N, 512, 384, 0, false);
    attn_scores<<<N, 256, 0, stream>>>(z0, al0, ar0, el0, er0, N, 4, 128);
    gat_aggregate<512,128><<<N, 256, 0, stream>>>(rowptr, esrc, el0, er0, z0, rst0, N);
    // rst0 = h1 [N,512] (relu applied)

    // ---- GAT layer 1 ----
    launch_gemm(rst0, 512, fc1,  256, nullptr, z1,   256, N, 256, 512, 0, false);
    launch_gemm(rst0, 512, res1, 256, nullptr, rst1, 256, N, 256, 512, 0, false);
    attn_scores<<<N, 256, 0, stream>>>(z1, al1, ar1, el1, er1, N, 4, 64);
    gat_aggregate<256,64><<<N, 256, 0, stream>>>(rowptr, esrc, el1, er1, z1, rst1, N);
    // rst1 = relu(h2) [N,256]  (layer act identity; relu fused since only the
    // decoder consumes it, and the decoder begins with relu)

    // ---- decoder ----
    launch_gemm(rst1, 256, fc1, 256, nullptr, d1, 512, N, 512, 256, 1, true);   // relu(h2) @ fc1^T
    launch_gemm(d1,   512, fc0, 512, nullptr, d2, 384, N, 384, 512, 1, true);   // d1 @ fc0^T
    mean_heads<<<(N * 96 + 255) / 256, 256, 0, stream>>>(d2, dm, N);
    launch_gemm(dm, 96, Wd[0], 512, bd[0], out,                      512, N, 512, 96, 2, false);
    launch_gemm(dm, 96, Wd[1], 512, bd[1], out + (size_t)N * 512,    512, N, 512, 96, 2, false);
    launch_gemm(dm, 96, Wd[2], 512, bd[2], out + (size_t)N * 512 * 2,512, N, 512, 96, 2, false);
}